// Round 9
// baseline (169.060 us; speedup 1.0000x reference)
//
#include <hip/hip_runtime.h>

// SmoothL1 + IoU-matching loss (levels [6400,1600,400], B=8, T=64, 9 groups).
// pred_i layout: (B, 36, L), element (b, a*4+c, l). target: (B, 64, 4).
//
// R4 changes vs R3:
//  - Division-free argmax: best kept as fraction (nb, db), db>0 invariant.
//    inter>0 ==> denom>0 (overlap forces positive pred box => area_p>0 and
//    inter<=min areas); inter==0 ==> iou is +/-0, normalized to (0,1).
//    Compare n_t*db > nb*d_t (2 muls) instead of IEEE div (~12 insts with
//    quarter-rate rcp chain). pos test: nb > 0.5*db (0.5*db exact).
//    Deviates from rounded-division compare only in <=1-ulp ties.
//  - Denominator built in exact reference association: ((ap+at)-inter)+eps.
//  - Fused finalize: done-counter, last block divides (3 graph nodes -> 2).
//  - BLK=64 one-wave blocks, 2448 blocks (~9.5/CU, ~2% tail vs 34% at 720).

#define NT   64
#define BLK  64
#define APT  4
#define SPAN (BLK * APT)             // 256 anchors per block
#define L0   6400
#define L1   1600
#define L2   400
#define CH0  25                      // 6400/256
#define CH1  7                       // ceil(1600/256)
#define CH2  2                       // ceil(400/256)
#define CHT  (CH0 + CH1 + CH2)       // 34 chunks per (b,a)
#define GRID (8 * 9 * CHT)           // 2448 blocks

__global__ __launch_bounds__(BLK) void anchor_loss_kernel(
    const float* __restrict__ pred0,
    const float* __restrict__ pred1,
    const float* __restrict__ pred2,
    const float* __restrict__ target,     // B*64*4 floats
    float*    __restrict__ g_loss,
    unsigned* __restrict__ g_cnt,
    unsigned* __restrict__ g_done,
    float*    __restrict__ out)
{
    const int bid   = blockIdx.x;
    const int chunk = bid % CHT;
    const int ba    = bid / CHT;
    const int a     = ba % 9;
    const int b     = ba / 9;

    const float* pred; int L; int lbase;
    if (chunk < CH0)            { pred = pred0; L = L0; lbase = chunk * SPAN; }
    else if (chunk < CH0 + CH1) { pred = pred1; L = L1; lbase = (chunk - CH0) * SPAN; }
    else                        { pred = pred2; L = L2; lbase = (chunk - CH0 - CH1) * SPAN; }

    // Stage 64 targets (box float4 + area). BLK==NT: one per thread.
    // Inner-loop reads are wave-uniform -> LDS broadcast, conflict-free.
    __shared__ float4 tbox[NT];
    __shared__ float  tarea[NT];
    const int tid = threadIdx.x;
    tbox[tid] = ((const float4*)(target + (size_t)b * NT * 4))[tid];
    __syncthreads();
    {
        const float4 t4 = tbox[tid];
        tarea[tid] = (t4.z - t4.x) * (t4.w - t4.y);
    }
    __syncthreads();

    // 4 contiguous anchors per thread; L % 4 == 0 so validity is uniform.
    const int  l0v   = lbase + tid * APT;
    const bool valid = (l0v < L);

    float p0[APT], p1[APT], p2[APT], p3[APT];
    if (valid) {
        const size_t base = ((size_t)b * 36 + (size_t)a * 4) * (size_t)L + (size_t)l0v;
        const float4 r0 = *(const float4*)(pred + base);
        const float4 r1 = *(const float4*)(pred + base + (size_t)L);
        const float4 r2 = *(const float4*)(pred + base + 2 * (size_t)L);
        const float4 r3 = *(const float4*)(pred + base + 3 * (size_t)L);
        p0[0] = r0.x; p0[1] = r0.y; p0[2] = r0.z; p0[3] = r0.w;
        p1[0] = r1.x; p1[1] = r1.y; p1[2] = r1.z; p1[3] = r1.w;
        p2[0] = r2.x; p2[1] = r2.y; p2[2] = r2.z; p2[3] = r2.w;
        p3[0] = r3.x; p3[1] = r3.y; p3[2] = r3.z; p3[3] = r3.w;
    } else {
        #pragma unroll
        for (int j = 0; j < APT; ++j) { p0[j] = p1[j] = p2[j] = p3[j] = 0.f; }
    }

    float ap[APT], nb[APT], db[APT];
    int   bi[APT];
    #pragma unroll
    for (int j = 0; j < APT; ++j) {
        ap[j] = (p2[j] - p0[j]) * (p3[j] - p1[j]);
        nb[j] = -1.0f;   // iou_0 > -1 always true -> t=0 taken, like reference
        db[j] = 1.0f;
        bi[j] = 0;
    }

    #pragma unroll 4
    for (int t = 0; t < NT; ++t) {
        const float4 tb = tbox[t];          // ds_read_b128 broadcast
        const float  at = tarea[t];         // ds_read_b32  broadcast
        #pragma unroll
        for (int j = 0; j < APT; ++j) {
            const float x1 = fmaxf(p0[j], tb.x);
            const float y1 = fmaxf(p1[j], tb.y);
            const float x2 = fminf(p2[j], tb.z);
            const float y2 = fminf(p3[j], tb.w);
            const float iw = fmaxf(x2 - x1, 0.0f);
            const float ih = fmaxf(y2 - y1, 0.0f);
            const float inter = iw * ih;
            // reference association: ((area_p + area_t) - inter) + eps
            float denom = ap[j] + at;
            denom = denom - inter;
            denom = denom + 1e-6f;
            // normalize: inter==0 -> iou is +/-0 == fraction (0, 1)
            const float d = (inter > 0.0f) ? denom : 1.0f;   // d > 0 always
            // iou_t > best  <=>  inter*db > nb*d   (both denominators > 0)
            if (inter * db[j] > nb[j] * d) {
                nb[j] = inter; db[j] = d; bi[j] = t;
            }
        }
    }

    float    lloss = 0.0f;
    unsigned lpos  = 0;
    if (valid) {
        #pragma unroll
        for (int j = 0; j < APT; ++j) {
            // best_iou > 0.5  <=>  nb > 0.5*db  (0.5*db exact, db>0)
            if (nb[j] > 0.5f * db[j]) {
                const float4 tb = tbox[bi[j]];
                float s = 0.0f;
                { float d = p0[j] - tb.x, ad = fabsf(d); s += (ad < 1.0f) ? 0.5f * ad * ad : ad - 0.5f; }
                { float d = p1[j] - tb.y, ad = fabsf(d); s += (ad < 1.0f) ? 0.5f * ad * ad : ad - 0.5f; }
                { float d = p2[j] - tb.z, ad = fabsf(d); s += (ad < 1.0f) ? 0.5f * ad * ad : ad - 0.5f; }
                { float d = p3[j] - tb.w, ad = fabsf(d); s += (ad < 1.0f) ? 0.5f * ad * ad : ad - 0.5f; }
                lloss += s;
                lpos  += 1;
            }
        }
    }

    // single-wave block: shuffle reduce, lane 0 does the atomics
    #pragma unroll
    for (int off = 32; off > 0; off >>= 1) {
        lloss += __shfl_down(lloss, off);
        lpos  += __shfl_down(lpos,  off);
    }
    if (tid == 0) {
        atomicAdd(g_loss, lloss);
        atomicAdd(g_cnt,  lpos);
        __threadfence();                       // partials visible before ticket
        const unsigned t = atomicAdd(g_done, 1u);
        if (t == GRID - 1) {                   // last block finalizes
            const float    total = atomicAdd(g_loss, 0.0f);  // coherent read
            const unsigned c     = atomicAdd(g_cnt,  0u);
            out[0] = total / (float)(c > 0u ? c : 1u);
        }
    }
}

extern "C" void kernel_launch(void* const* d_in, const int* in_sizes, int n_in,
                              void* d_out, int out_size, void* d_ws, size_t ws_size,
                              hipStream_t stream)
{
    (void)in_sizes; (void)n_in; (void)out_size; (void)ws_size;
    const float* pred0  = (const float*)d_in[0];
    const float* pred1  = (const float*)d_in[1];
    const float* pred2  = (const float*)d_in[2];
    const float* target = (const float*)d_in[3];

    float*    g_loss = (float*)d_ws;
    unsigned* g_cnt  = (unsigned*)((char*)d_ws + 4);
    unsigned* g_done = (unsigned*)((char*)d_ws + 8);

    // d_ws is re-poisoned 0xAA before every timed launch -> zero the 3 cells.
    hipMemsetAsync(d_ws, 0, 12, stream);

    anchor_loss_kernel<<<GRID, BLK, 0, stream>>>(pred0, pred1, pred2, target,
                                                 g_loss, g_cnt, g_done,
                                                 (float*)d_out);
}

// Round 10
// 93.584 us; speedup vs baseline: 1.8065x; 1.8065x over previous
//
#include <hip/hip_runtime.h>

// SmoothL1 + IoU-matching loss (levels [6400,1600,400], B=8, T=64, 9 groups).
// pred_i layout: (B, 36, L), element (b, a*4+c, l). target: (B, 64, 4).
//
// R10 = R3 structure (validated 45.5us, VALUBusy 70%) + R9's validated
// division-free argmax (absmax 0.0 on HW).
//  - R9 lesson: fused finalize w/ __threadfence + same-line ticket atomics
//    serialized the dispatch (109us, VALUBusy 19%). Reverted: separate
//    1-thread finalize kernel; e2e overhead measured fixed (~60us)
//    regardless of graph node count, so fusion gains nothing.
//  - Division-free argmax: best as fraction (nb, db), db>0 invariant.
//    inter>0 ==> denom >= inter+eps > 0; inter==0 ==> iou = +/-0 == (0,1).
//    Compare inter*db > nb*d (2 muls) replaces IEEE div (~12-inst rcp
//    chain). pos test nb > 0.5*db is the exact rational comparison.
//  - Denominator in exact reference association: ((ap+at)-inter)+eps.

#define NT   64
#define BLK  256
#define APT  4
#define SPAN (BLK * APT)             // 1024 anchors per block
#define L0   6400
#define L1   1600
#define L2   400
#define CH0  7                       // ceil(6400/1024)
#define CH1  2                       // ceil(1600/1024)
#define CH2  1                       // ceil(400/1024)
#define CHT  (CH0 + CH1 + CH2)       // 10 chunks per (b,a)

__global__ __launch_bounds__(BLK) void anchor_loss_kernel(
    const float* __restrict__ pred0,
    const float* __restrict__ pred1,
    const float* __restrict__ pred2,
    const float* __restrict__ target,   // B*64*4 floats
    float* __restrict__ g_loss,
    int*   __restrict__ g_cnt)
{
    const int bid   = blockIdx.x;
    const int chunk = bid % CHT;
    const int ba    = bid / CHT;
    const int a     = ba % 9;
    const int b     = ba / 9;

    const float* pred; int L; int lbase;
    if (chunk < CH0)            { pred = pred0; L = L0; lbase = chunk * SPAN; }
    else if (chunk < CH0 + CH1) { pred = pred1; L = L1; lbase = (chunk - CH0) * SPAN; }
    else                        { pred = pred2; L = L2; lbase = (chunk - CH0 - CH1) * SPAN; }

    // Stage 64 targets (box float4 + area). Inner-loop reads are
    // wave-uniform -> LDS broadcast, conflict-free.
    __shared__ float4 tbox[NT];
    __shared__ float  tarea[NT];
    const int tid = threadIdx.x;
    if (tid < NT)
        tbox[tid] = ((const float4*)(target + (size_t)b * NT * 4))[tid];
    __syncthreads();
    if (tid < NT) {
        const float4 t4 = tbox[tid];
        tarea[tid] = (t4.z - t4.x) * (t4.w - t4.y);
    }
    __syncthreads();

    // 4 contiguous anchors per thread; all L % SPAN chunks are %4 so
    // validity is uniform across the 4.
    const int  l0v   = lbase + tid * APT;
    const bool valid = (l0v < L);

    float p0[APT], p1[APT], p2[APT], p3[APT];
    if (valid) {
        const size_t base = ((size_t)b * 36 + (size_t)a * 4) * (size_t)L + (size_t)l0v;
        const float4 r0 = *(const float4*)(pred + base);
        const float4 r1 = *(const float4*)(pred + base + (size_t)L);
        const float4 r2 = *(const float4*)(pred + base + 2 * (size_t)L);
        const float4 r3 = *(const float4*)(pred + base + 3 * (size_t)L);
        p0[0] = r0.x; p0[1] = r0.y; p0[2] = r0.z; p0[3] = r0.w;
        p1[0] = r1.x; p1[1] = r1.y; p1[2] = r1.z; p1[3] = r1.w;
        p2[0] = r2.x; p2[1] = r2.y; p2[2] = r2.z; p2[3] = r2.w;
        p3[0] = r3.x; p3[1] = r3.y; p3[2] = r3.z; p3[3] = r3.w;
    } else {
        #pragma unroll
        for (int j = 0; j < APT; ++j) { p0[j] = p1[j] = p2[j] = p3[j] = 0.f; }
    }

    float ap[APT], nb[APT], db[APT];
    int   bi[APT];
    #pragma unroll
    for (int j = 0; j < APT; ++j) {
        ap[j] = (p2[j] - p0[j]) * (p3[j] - p1[j]);
        nb[j] = -1.0f;   // iou_0 > -1 always -> t=0 taken, like reference
        db[j] = 1.0f;
        bi[j] = 0;
    }

    #pragma unroll 4
    for (int t = 0; t < NT; ++t) {
        const float4 tb = tbox[t];          // ds_read_b128 broadcast
        const float  at = tarea[t];         // ds_read_b32  broadcast
        #pragma unroll
        for (int j = 0; j < APT; ++j) {
            const float x1 = fmaxf(p0[j], tb.x);
            const float y1 = fmaxf(p1[j], tb.y);
            const float x2 = fminf(p2[j], tb.z);
            const float y2 = fminf(p3[j], tb.w);
            const float iw = fmaxf(x2 - x1, 0.0f);
            const float ih = fmaxf(y2 - y1, 0.0f);
            const float inter = iw * ih;
            // reference association: ((area_p + area_t) - inter) + eps
            float denom = ap[j] + at;
            denom = denom - inter;
            denom = denom + 1e-6f;
            // inter==0 -> iou is +/-0, use exact fraction (0, 1)
            const float d = (inter > 0.0f) ? denom : 1.0f;   // d > 0 always
            // iou_t > best  <=>  inter*db > nb*d  (both denoms > 0)
            if (inter * db[j] > nb[j] * d) {
                nb[j] = inter; db[j] = d; bi[j] = t;
            }
        }
    }

    float lloss = 0.0f;
    int   lpos  = 0;
    if (valid) {
        #pragma unroll
        for (int j = 0; j < APT; ++j) {
            // best_iou > 0.5  <=>  nb > 0.5*db  (exact: db>0, 0.5*db exact)
            if (nb[j] > 0.5f * db[j]) {
                const float4 tb = tbox[bi[j]];
                float s = 0.0f;
                { float d = p0[j] - tb.x, ad = fabsf(d); s += (ad < 1.0f) ? 0.5f * ad * ad : ad - 0.5f; }
                { float d = p1[j] - tb.y, ad = fabsf(d); s += (ad < 1.0f) ? 0.5f * ad * ad : ad - 0.5f; }
                { float d = p2[j] - tb.z, ad = fabsf(d); s += (ad < 1.0f) ? 0.5f * ad * ad : ad - 0.5f; }
                { float d = p3[j] - tb.w, ad = fabsf(d); s += (ad < 1.0f) ? 0.5f * ad * ad : ad - 0.5f; }
                lloss += s;
                lpos  += 1;
            }
        }
    }

    // wave(64) shuffle reduce, cross-wave via LDS, one atomic pair per block
    #pragma unroll
    for (int off = 32; off > 0; off >>= 1) {
        lloss += __shfl_down(lloss, off);
        lpos  += __shfl_down(lpos,  off);
    }
    __shared__ float wl[BLK / 64];
    __shared__ int   wc[BLK / 64];
    const int wave = tid >> 6;
    if ((tid & 63) == 0) { wl[wave] = lloss; wc[wave] = lpos; }
    __syncthreads();
    if (tid == 0) {
        float s = 0.0f; int c = 0;
        #pragma unroll
        for (int w = 0; w < BLK / 64; ++w) { s += wl[w]; c += wc[w]; }
        atomicAdd(g_loss, s);
        atomicAdd(g_cnt, c);
    }
}

__global__ void finalize_kernel(const float* __restrict__ g_loss,
                                const int*   __restrict__ g_cnt,
                                float* __restrict__ out)
{
    const int n = *g_cnt;
    out[0] = (*g_loss) / (float)(n > 0 ? n : 1);
}

extern "C" void kernel_launch(void* const* d_in, const int* in_sizes, int n_in,
                              void* d_out, int out_size, void* d_ws, size_t ws_size,
                              hipStream_t stream)
{
    (void)in_sizes; (void)n_in; (void)out_size; (void)ws_size;
    const float* pred0  = (const float*)d_in[0];
    const float* pred1  = (const float*)d_in[1];
    const float* pred2  = (const float*)d_in[2];
    const float* target = (const float*)d_in[3];

    float* g_loss = (float*)d_ws;
    int*   g_cnt  = (int*)((char*)d_ws + sizeof(float));

    // d_ws is re-poisoned 0xAA before every timed launch -> zero accumulators.
    hipMemsetAsync(d_ws, 0, 2 * sizeof(float), stream);

    const int grid = 8 * 9 * CHT;   // 720 blocks x 256 thr x 4 anchors/thread
    anchor_loss_kernel<<<grid, BLK, 0, stream>>>(pred0, pred1, pred2, target,
                                                 g_loss, g_cnt);
    finalize_kernel<<<1, 1, 0, stream>>>(g_loss, g_cnt, (float*)d_out);
}